// Round 3
// baseline (259.713 us; speedup 1.0000x reference)
//
#include <hip/hip_runtime.h>
#include <hip/hip_cooperative_groups.h>

namespace cg = cooperative_groups;

#define N_NODES 50000
#define N_EDGES 1200000
#define N_TILES (N_NODES / 16)   // 3125, exact
#define W1T_STRIDE 72            // bf16 elems per j-row in LDS (16B aligned)

#define N_BUCKETS 196            // ceil(50000/256) row buckets of 256 nodes
#define BUCKET_CAP 7168          // mean 6122, sigma ~78 -> 13 sigma headroom
#define EDGES_PER_BLOCK 4800     // R12: union LDS 11.2KB -> coop-occupancy safe
#define KA_BLOCKS 250            // 1.2M / 4800 exact
#define GEMM_BLOCKS 782          // 782*4 waves = 3128 tiles >= 3125
#define A1_TASKS (KA_BLOCKS + GEMM_BLOCKS)   // 1032
#define KB_SPLIT 8               // segments/bucket; 8 seg x 4 waves = 32 slots
#define KB_TASKS (N_BUCKETS * KB_SPLIT)      // 1568
#define COOP_GRID 512            // 2 blocks/CU -- under every occupancy model

typedef __attribute__((ext_vector_type(8))) short short8;   // 8 bf16
typedef __attribute__((ext_vector_type(4))) float floatx4;  // MFMA acc

__device__ __forceinline__ unsigned short f32_to_bf16(float f) {
    unsigned int v = __float_as_uint(f);
    unsigned int r = v + 0x7FFFu + ((v >> 16) & 1u);
    return (unsigned short)(r >> 16);
}
__device__ __forceinline__ float bf16_to_f32(unsigned short s) {
    return __uint_as_float(((unsigned int)s) << 16);
}
__device__ __forceinline__ unsigned int pack_bf16x2(float lo, float hi) {
    return (unsigned int)f32_to_bf16(lo) | ((unsigned int)f32_to_bf16(hi) << 16);
}

// ---------------------------------------------------------------------------
// R12: one kernel, three run modes.
//   mode 0 (cooperative): A0 zero out+cursor -> grid.sync -> A1 {binning ||
//     layer-1 MFMA GEMM} as grid-stride tasks -> grid.sync -> B bucket MLP.
//   mode 1: phases A0+A1 only (cursor zeroed by host memset).   } fallback
//   mode 2: phase B only.                                        } path
// R11's coop launch was almost certainly REFUSED (out stayed zero -> absmax
// = max|ref|): grid 1024 needed 4 blocks/CU but the 20.8KB LDS union caps
// occupancy at 3 under a 64KiB LDS budget. Now: grid 512 (2/CU), LDS 11.2KB,
// and the launch error is checked with a proven 3-dispatch fallback.
// ---------------------------------------------------------------------------
__global__ __launch_bounds__(256, 4) void edgemlp_all(
    const float* __restrict__ x, const float* __restrict__ W1,
    const float* __restrict__ b1,
    const int* __restrict__ row, const int* __restrict__ col,
    const float* __restrict__ u,
    const float* __restrict__ W2, const float* __restrict__ b2,
    const float* __restrict__ W3, const float* __restrict__ b3,
    unsigned short* __restrict__ P1, unsigned short* __restrict__ P2,
    unsigned int* __restrict__ buf, int* __restrict__ cursor,
    float* __restrict__ out, int mode)
{
    __shared__ union {
        unsigned short W1t[64 * W1T_STRIDE];                // 9216 B (GEMM)
        struct {
            unsigned short rankv[EDGES_PER_BLOCK];          // 9600 B (binning)
            int hist[N_BUCKETS];                            //  784 B
            int base[N_BUCKETS];                            //  784 B
        } bin;
        float accs[256];                                    // 1024 B (MLP)
    } sh;

    cg::grid_group grid = cg::this_grid();

    const int tid = threadIdx.x;
    const int bid = blockIdx.x;
    const int gstride = (int)gridDim.x;
    const int gtid = bid * 256 + tid;

    const int lane = tid & 63;
    const int n = lane & 15;
    const int q = lane >> 4;
    const int wave = tid >> 6;                  // 0..3
    const bool coop = (mode == 0);

    if (mode <= 1) {
        // ================= phase A0: zero out (+cursor in coop) =============
        for (int i = gtid; i < N_NODES; i += gstride * 256) out[i] = 0.0f;
        if (coop) {
            if (gtid < N_BUCKETS) cursor[gtid] = 0;
            grid.sync();
        }

        // ================= phase A1: binning || GEMM (grid-stride) ==========
        for (int task = bid; task < A1_TASKS; task += gstride) {
            if (task < KA_BLOCKS) {
                // ---- binning path (R0/R10-proven machinery) ----
                for (int b = tid; b < N_BUCKETS; b += 256) sh.bin.hist[b] = 0;
                __syncthreads();

                const int blockStart = task * EDGES_PER_BLOCK;

                for (int i = tid; i < EDGES_PER_BLOCK; i += 256) {
                    const int r = row[blockStart + i];
                    sh.bin.rankv[i] =
                        (unsigned short)atomicAdd(&sh.bin.hist[r >> 8], 1);
                }
                __syncthreads();

                for (int b = tid; b < N_BUCKETS; b += 256)
                    sh.bin.base[b] = atomicAdd(&cursor[b], sh.bin.hist[b]);
                __syncthreads();

                for (int i = tid; i < EDGES_PER_BLOCK; i += 256) {
                    const int r = row[blockStart + i];
                    const int c = col[blockStart + i];
                    const int bin = r >> 8;
                    buf[(size_t)bin * BUCKET_CAP + sh.bin.base[bin]
                        + (int)sh.bin.rankv[i]] =
                        ((unsigned int)(r & 255) << 24) | (unsigned int)c;
                }
            } else {
                // ---- layer-1 precompute path (R4-proven MFMA GEMM) ----
                for (int e = tid; e < 128 * 32; e += 256) {
                    const int kp = e >> 5, jp = e & 31;
                    sh.W1t[((kp < 64) ? jp : jp + 32) * W1T_STRIDE + (kp & 63)] =
                        f32_to_bf16(W1[e]);
                }
                __syncthreads();

                const int tile = (task - KA_BLOCKS) * 4 + wave;
                if (tile < N_TILES) {
                    short8 bw[4][2];
                    #pragma unroll
                    for (int G = 0; G < 4; ++G)
                        #pragma unroll
                        for (int h = 0; h < 2; ++h)
                            bw[G][h] = *(const short8*)
                                &sh.W1t[(n + 16 * G) * W1T_STRIDE + h * 32 + q * 8];
                    const float bias0 = b1[n], bias1 = b1[n + 16];

                    const int node = tile * 16 + n;
                    const float4* xp  = (const float4*)(x + (size_t)node * 64 + q * 8);
                    const float4 xa = xp[0], xb = xp[1];
                    const float4* xp2 = (const float4*)(x + (size_t)node * 64 + 32 + q * 8);
                    const float4 xc = xp2[0], xd = xp2[1];

                    short8 a0, a1;
                    a0[0] = (short)f32_to_bf16(xa.x); a0[1] = (short)f32_to_bf16(xa.y);
                    a0[2] = (short)f32_to_bf16(xa.z); a0[3] = (short)f32_to_bf16(xa.w);
                    a0[4] = (short)f32_to_bf16(xb.x); a0[5] = (short)f32_to_bf16(xb.y);
                    a0[6] = (short)f32_to_bf16(xb.z); a0[7] = (short)f32_to_bf16(xb.w);
                    a1[0] = (short)f32_to_bf16(xc.x); a1[1] = (short)f32_to_bf16(xc.y);
                    a1[2] = (short)f32_to_bf16(xc.z); a1[3] = (short)f32_to_bf16(xc.w);
                    a1[4] = (short)f32_to_bf16(xd.x); a1[5] = (short)f32_to_bf16(xd.y);
                    a1[6] = (short)f32_to_bf16(xd.z); a1[7] = (short)f32_to_bf16(xd.w);

                    floatx4 acc[4];
                    #pragma unroll
                    for (int G = 0; G < 4; ++G) {
                        const float bi = (G == 0) ? bias0 : (G == 1) ? bias1 : 0.0f;
                        acc[G] = (floatx4){bi, bi, bi, bi};
                        acc[G] = __builtin_amdgcn_mfma_f32_16x16x32_bf16(a0, bw[G][0], acc[G], 0, 0, 0);
                        acc[G] = __builtin_amdgcn_mfma_f32_16x16x32_bf16(a1, bw[G][1], acc[G], 0, 0, 0);
                    }
                    unsigned int* P1d = (unsigned int*)P1;
                    unsigned int* P2d = (unsigned int*)P2;
                    #pragma unroll
                    for (int r = 0; r < 4; ++r) {
                        const int nr = tile * 16 + q * 4 + r;
                        P1d[(size_t)nr * 16 + n] = pack_bf16x2(acc[0][r], acc[1][r]);
                        P2d[(size_t)nr * 16 + n] = pack_bf16x2(acc[2][r], acc[3][r]);
                    }
                }
            }
            __syncthreads();   // union reused by the next grid-stride task
        }
    }

    if (coop) grid.sync();
    if (mode == 1) return;

    // ================= phase B: per-bucket MLP (layers 2+3) =================
    short8 bf0, bf1;
    #pragma unroll
    for (int i = 0; i < 8; ++i) {
        const int F = q * 4 + (i >> 1) + 16 * (i & 1);
        bf0[i] = (short)f32_to_bf16(W2[F * 32 + n]);
        bf1[i] = (short)f32_to_bf16(W2[F * 32 + n + 16]);
    }
    const float w3n0 = W3[n], w3n1 = W3[n + 16];
    const float b2n0 = b2[n], b2n1 = b2[n + 16];
    const float bias3 = b3[0];

    for (int task = bid; task < KB_TASKS; task += gstride) {
        const int b = task >> 3;              // bucket
        const int s = task & (KB_SPLIT - 1);  // segment

        sh.accs[tid] = 0.0f;
        __syncthreads();

        const int cnt = cursor[b];
        const unsigned int* bb = buf + (size_t)b * BUCKET_CAP;
        const unsigned short* P1b = P1 + (size_t)b * 256 * 32;  // row window
        const int nch = (cnt + 31) >> 5;

        #pragma unroll 1
        for (int ch = s * 4 + wave; ch < nch; ch += 32) {
            const int base0 = ch * 32;

            // ---- gather-lane entries (clamped at tail) ----
            int rl[2], cI[2];
            #pragma unroll
            for (int t = 0; t < 2; ++t) {
                int e = base0 + t * 16 + n;
                if (e >= cnt) e = cnt - 1;
                const unsigned int ent = bb[e];
                rl[t] = (int)(ent >> 24);
                cI[t] = (int)(ent & 0x1FFFFu);
            }
            // ---- owner-lane entry (zeroed at tail) ----
            int r2 = 0; float u2 = 0.0f;
            if (n < 8) {
                const int eloc = base0 + 16 * (n >> 2) + 4 * q + (n & 3);
                const unsigned int ent2 = bb[(eloc < cnt) ? eloc : 0];
                r2 = (int)(ent2 >> 24);
                u2 = (eloc < cnt) ? u[ent2 & 0x1FFFFu] : 0.0f;
            }
            // ---- P gathers: row from 16KB window (L1), col from P2 (L2) ----
            short8 v1[2], v2[2];
            #pragma unroll
            for (int t = 0; t < 2; ++t) {
                v1[t] = *(const short8*)(P1b + (size_t)rl[t] * 32 + q * 8);
                v2[t] = *(const short8*)(P2 + (size_t)cI[t] * 32 + q * 8);
            }

            // ---- layers 2+3 (R4-proven core) ----
            float tr[2][4];
            #pragma unroll
            for (int t = 0; t < 2; ++t) {
                short8 a;
                #pragma unroll
                for (int i = 0; i < 8; ++i) {
                    const float f1 = bf16_to_f32((unsigned short)v1[t][i]);
                    const float f2 = bf16_to_f32((unsigned short)v2[t][i]);
                    a[i] = (short)f32_to_bf16(fmaxf(f1 + f2, 0.0f));
                }
                floatx4 d0 = {b2n0, b2n0, b2n0, b2n0};
                floatx4 d1 = {b2n1, b2n1, b2n1, b2n1};
                d0 = __builtin_amdgcn_mfma_f32_16x16x32_bf16(a, bf0, d0, 0, 0, 0);
                d1 = __builtin_amdgcn_mfma_f32_16x16x32_bf16(a, bf1, d1, 0, 0, 0);
                #pragma unroll
                for (int r = 0; r < 4; ++r)
                    tr[t][r] = fmaxf(d0[r], 0.0f) * w3n0 + fmaxf(d1[r], 0.0f) * w3n1;
            }

            #pragma unroll
            for (int mask = 1; mask < 16; mask <<= 1) {
                #pragma unroll
                for (int t = 0; t < 2; ++t)
                    #pragma unroll
                    for (int r = 0; r < 4; ++r)
                        tr[t][r] += __shfl_xor(tr[t][r], mask, 64);
            }

            if (n < 8) {
                const float va0 = (n & 4) ? tr[1][0] : tr[0][0];
                const float va1 = (n & 4) ? tr[1][1] : tr[0][1];
                const float va2 = (n & 4) ? tr[1][2] : tr[0][2];
                const float va3 = (n & 4) ? tr[1][3] : tr[0][3];
                const float vb0 = (n & 2) ? va2 : va0;
                const float vb1 = (n & 2) ? va3 : va1;
                const float v   = (n & 1) ? vb1 : vb0;
                atomicAdd(&sh.accs[r2], (v + bias3) * u2);
            }
        }

        __syncthreads();

        const int node = b * 256 + tid;
        if (node < N_NODES) atomicAdd(out + node, sh.accs[tid]);
        __syncthreads();   // accs reused by the next grid-stride task
    }
}

extern "C" void kernel_launch(void* const* d_in, const int* in_sizes, int n_in,
                              void* d_out, int out_size, void* d_ws, size_t ws_size,
                              hipStream_t stream)
{
    const float* x    = (const float*)d_in[0];
    const int*   eidx = (const int*)  d_in[1];   // [2, E] int32
    const float* u    = (const float*)d_in[2];
    const float* W1   = (const float*)d_in[3];
    const float* b1   = (const float*)d_in[4];
    const float* W2   = (const float*)d_in[5];
    const float* b2   = (const float*)d_in[6];
    const float* W3   = (const float*)d_in[7];
    const float* b3   = (const float*)d_in[8];

    const int* row = eidx;
    const int* col = eidx + N_EDGES;

    // ws layout: P1 3.2MB | P2 3.2MB | buf 5.62MB | cursor 784B
    unsigned short* P1 = (unsigned short*)d_ws;
    unsigned short* P2 = (unsigned short*)((char*)d_ws + (size_t)N_NODES * 64);
    unsigned int*  buf = (unsigned int*)((char*)d_ws + (size_t)N_NODES * 128);
    int* cursor = (int*)((char*)d_ws + (size_t)N_NODES * 128
                         + (size_t)N_BUCKETS * BUCKET_CAP * 4);
    float* out = (float*)d_out;

    int mode0 = 0;
    void* args[] = {
        (void*)&x, (void*)&W1, (void*)&b1, (void*)&row, (void*)&col,
        (void*)&u, (void*)&W2, (void*)&b2, (void*)&W3, (void*)&b3,
        (void*)&P1, (void*)&P2, (void*)&buf, (void*)&cursor, (void*)&out,
        (void*)&mode0
    };
    hipError_t err = hipLaunchCooperativeKernel(
        (const void*)edgemlp_all, dim3(COOP_GRID), dim3(256), args, 0, stream);

    if (err != hipSuccess) {
        // -------- proven 3-dispatch fallback (R0 structure) --------
        (void)hipGetLastError();   // clear the sticky error
        hipMemsetAsync(cursor, 0, N_BUCKETS * sizeof(int), stream);
        edgemlp_all<<<A1_TASKS, 256, 0, stream>>>(
            x, W1, b1, row, col, u, W2, b2, W3, b3,
            P1, P2, buf, cursor, out, 1);
        edgemlp_all<<<KB_TASKS, 256, 0, stream>>>(
            x, W1, b1, row, col, u, W2, b2, W3, b3,
            P1, P2, buf, cursor, out, 2);
    }
}

// Round 4
// 130.776 us; speedup vs baseline: 1.9859x; 1.9859x over previous
//
#include <hip/hip_runtime.h>
#include <hip/hip_bf16.h>

#define N_NODES 50000
#define N_EDGES 1200000
#define N_TILES (N_NODES / 16)   // 3125, exact
#define W1T_STRIDE 72            // bf16 elems per j-row in LDS (16B aligned)
#define K1_BLOCKS 782            // 3128 waves >= 3125 tiles, one-shot

#define N_BUCKETS 196            // ceil(50000/256) row buckets of 256 nodes
#define BUCKET_CAP 7168          // mean 6122, sigma ~78 -> 13 sigma headroom
#define EDGES_PER_BLOCK 1920     // R0-proven binning block size
#define KA_BLOCKS 625            // 1.2M / 1920 exact
#define D1_BLOCKS (K1_BLOCKS + KA_BLOCKS)   // 1407: precompute + bin fused
#define KB_SPLIT 4               // segments per bucket in the MLP kernel

typedef __attribute__((ext_vector_type(8))) short short8;   // 8 bf16
typedef __attribute__((ext_vector_type(4))) float floatx4;  // MFMA acc

__device__ __forceinline__ unsigned short f32_to_bf16(float f) {
    unsigned int v = __float_as_uint(f);
    unsigned int r = v + 0x7FFFu + ((v >> 16) & 1u);
    return (unsigned short)(r >> 16);
}
__device__ __forceinline__ float bf16_to_f32(unsigned short s) {
    return __uint_as_float(((unsigned int)s) << 16);
}
// packed RTNE bf16x2 (v_cvt_pk_bf16_f32 path; same rounding as manual pack)
__device__ __forceinline__ unsigned int pk_bf16x2_rn(float lo, float hi) {
    union { __hip_bfloat162 h; unsigned int u; } cv;
    cv.h = __float22bfloat162_rn(make_float2(lo, hi));
    return cv.u;
}
// f32 add with DPP row-rotate source: pure-VALU 16-lane reduce stage
#define DPP_ROR_F32(x, N) \
    __int_as_float(__builtin_amdgcn_update_dpp( \
        0, __float_as_int(x), 0x120 + (N), 0xF, 0xF, false))

// ---------------------------------------------------------------------------
// R13 = R0 structure (best measured, 133.8us; R11/R12 proved the 3-dispatch
// split is what buys parallelism: merged coop @2 blocks/CU ran 162us with
// Occupancy==grid cap, 5% HBM, 10% VALU -> latency/parallelism-bound).
// Changes vs R0, confined to issue-pressure hot spots seen in R12 counters:
//   * bucket_mlp reduce: __shfl_xor (32 ds_bpermute/chunk, ~1.2M DS ops) ->
//     4x v_add_f32+DPP row_ror:{1,2,4,8} per value (reduce-to-all, no LDS).
//   * bf16 packing via v_cvt_pk_bf16_f32 (RTNE, bit-identical) in the D2
//     repack and D1 A-fragment/P-store packs.
// ---------------------------------------------------------------------------
__global__ __launch_bounds__(256) void fused_pre_bin(
    const float* __restrict__ x, const float* __restrict__ W1,
    const float* __restrict__ b1,
    const int* __restrict__ row, const int* __restrict__ col,
    unsigned short* __restrict__ P1, unsigned short* __restrict__ P2,
    unsigned int* __restrict__ buf, int* __restrict__ cursor,
    float* __restrict__ out)
{
    __shared__ union {
        unsigned short W1t[64 * W1T_STRIDE];                // 9216 B
        struct {
            unsigned short rankv[EDGES_PER_BLOCK];          // 3840 B
            int hist[N_BUCKETS];                            //  784 B
            int base[N_BUCKETS];                            //  784 B
        } bin;
    } sh;

    const int tid = threadIdx.x;
    const int bid = blockIdx.x;

    if (bid < K1_BLOCKS) {
        // ================= precompute path =================
        const int gtid = bid * 256 + tid;
        for (int i = gtid; i < N_NODES; i += K1_BLOCKS * 256)
            out[i] = 0.0f;   // KB atomically accumulates into out

        for (int e = tid; e < 128 * 32; e += 256) {
            const int kp = e >> 5, jp = e & 31;
            sh.W1t[((kp < 64) ? jp : jp + 32) * W1T_STRIDE + (kp & 63)] =
                f32_to_bf16(W1[e]);
        }
        __syncthreads();

        const int lane = tid & 63;
        const int n = lane & 15;
        const int q = lane >> 4;

        const int tile = bid * 4 + (tid >> 6);
        if (tile >= N_TILES) return;

        short8 bw[4][2];
        #pragma unroll
        for (int G = 0; G < 4; ++G)
            #pragma unroll
            for (int h = 0; h < 2; ++h)
                bw[G][h] = *(const short8*)
                    &sh.W1t[(n + 16 * G) * W1T_STRIDE + h * 32 + q * 8];
        const float bias0 = b1[n], bias1 = b1[n + 16];

        const int node = tile * 16 + n;
        const float4* xp  = (const float4*)(x + (size_t)node * 64 + q * 8);
        const float4 xa = xp[0], xb = xp[1];
        const float4* xp2 = (const float4*)(x + (size_t)node * 64 + 32 + q * 8);
        const float4 xc = xp2[0], xd = xp2[1];

        union S8 { short8 s; unsigned int w[4]; } A0, A1;
        A0.w[0] = pk_bf16x2_rn(xa.x, xa.y);
        A0.w[1] = pk_bf16x2_rn(xa.z, xa.w);
        A0.w[2] = pk_bf16x2_rn(xb.x, xb.y);
        A0.w[3] = pk_bf16x2_rn(xb.z, xb.w);
        A1.w[0] = pk_bf16x2_rn(xc.x, xc.y);
        A1.w[1] = pk_bf16x2_rn(xc.z, xc.w);
        A1.w[2] = pk_bf16x2_rn(xd.x, xd.y);
        A1.w[3] = pk_bf16x2_rn(xd.z, xd.w);
        const short8 a0 = A0.s, a1 = A1.s;

        floatx4 acc[4];
        #pragma unroll
        for (int G = 0; G < 4; ++G) {
            const float bi = (G == 0) ? bias0 : (G == 1) ? bias1 : 0.0f;
            acc[G] = (floatx4){bi, bi, bi, bi};
            acc[G] = __builtin_amdgcn_mfma_f32_16x16x32_bf16(a0, bw[G][0], acc[G], 0, 0, 0);
            acc[G] = __builtin_amdgcn_mfma_f32_16x16x32_bf16(a1, bw[G][1], acc[G], 0, 0, 0);
        }
        unsigned int* P1d = (unsigned int*)P1;
        unsigned int* P2d = (unsigned int*)P2;
        #pragma unroll
        for (int r = 0; r < 4; ++r) {
            const int nr = tile * 16 + q * 4 + r;
            P1d[(size_t)nr * 16 + n] = pk_bf16x2_rn(acc[0][r], acc[1][r]);
            P2d[(size_t)nr * 16 + n] = pk_bf16x2_rn(acc[2][r], acc[3][r]);
        }
    } else {
        // ================= binning path =================
        for (int b = tid; b < N_BUCKETS; b += 256) sh.bin.hist[b] = 0;
        __syncthreads();

        const int blockStart = (bid - K1_BLOCKS) * EDGES_PER_BLOCK;

        for (int i = tid; i < EDGES_PER_BLOCK; i += 256) {
            const int r = row[blockStart + i];
            sh.bin.rankv[i] = (unsigned short)atomicAdd(&sh.bin.hist[r >> 8], 1);
        }
        __syncthreads();

        for (int b = tid; b < N_BUCKETS; b += 256)
            sh.bin.base[b] = atomicAdd(&cursor[b], sh.bin.hist[b]);
        __syncthreads();

        for (int i = tid; i < EDGES_PER_BLOCK; i += 256) {
            const int r = row[blockStart + i];
            const int c = col[blockStart + i];
            const int bin = r >> 8;
            buf[(size_t)bin * BUCKET_CAP + sh.bin.base[bin] + (int)sh.bin.rankv[i]] =
                ((unsigned int)(r & 255) << 24) | (unsigned int)c;
        }
    }
}

// ---------------------------------------------------------------------------
// Dispatch 2 (KB): per-bucket MLP (layers 2+3, MFMA) + LDS fp32 row reduce.
// 512-thread blocks: 8 waves share one accs[256]. Block = (bucket b, segment
// s); wave-slot = s*8+wave, chunk stride = 32. Row gathers hit the 16 KB P1
// bucket window (L1); col gathers hit L2-resident P2 (3.2 MB).
// R13: 16-lane reduce is now 4x v_add_f32+DPP row_ror (was 32 ds_bpermute).
// ---------------------------------------------------------------------------
__global__ __launch_bounds__(512) void bucket_mlp(
    const float* __restrict__ u,
    const float* __restrict__ W2, const float* __restrict__ b2,
    const float* __restrict__ W3, const float* __restrict__ b3,
    const unsigned short* __restrict__ P1, const unsigned short* __restrict__ P2,
    const unsigned int* __restrict__ buf, const int* __restrict__ cursor,
    float* __restrict__ out)
{
    __shared__ float accs[256];
    const int tid = threadIdx.x;
    if (tid < 256) accs[tid] = 0.0f;

    const int b = blockIdx.x >> 2;              // bucket
    const int s = blockIdx.x & (KB_SPLIT - 1);  // segment

    const int lane = tid & 63;
    const int n = lane & 15;
    const int q = lane >> 4;
    const int wave = tid >> 6;                  // 0..7

    // W2/W3 fragments with the P permutation F(q,i)
    short8 bf0, bf1;
    #pragma unroll
    for (int i = 0; i < 8; ++i) {
        const int F = q * 4 + (i >> 1) + 16 * (i & 1);
        bf0[i] = (short)f32_to_bf16(W2[F * 32 + n]);
        bf1[i] = (short)f32_to_bf16(W2[F * 32 + n + 16]);
    }
    const float w3n0 = W3[n], w3n1 = W3[n + 16];
    const float b2n0 = b2[n], b2n1 = b2[n + 16];
    const float bias3 = b3[0];

    __syncthreads();

    const int cnt = cursor[b];
    const unsigned int* bb = buf + (size_t)b * BUCKET_CAP;
    const unsigned short* P1b = P1 + (size_t)b * 256 * 32;  // bucket row window
    const int nch = (cnt + 31) >> 5;

    #pragma unroll 1
    for (int ch = s * 8 + wave; ch < nch; ch += KB_SPLIT * 8) {
        const int base0 = ch * 32;

        // ---- gather-lane entries (clamped at tail) ----
        int rl[2], cI[2];
        #pragma unroll
        for (int t = 0; t < 2; ++t) {
            int e = base0 + t * 16 + n;
            if (e >= cnt) e = cnt - 1;
            const unsigned int ent = bb[e];
            rl[t] = (int)(ent >> 24);
            cI[t] = (int)(ent & 0x1FFFFu);
        }
        // ---- owner-lane entry (zeroed at tail) ----
        int r2 = 0; float u2 = 0.0f;
        if (n < 8) {
            const int eloc = base0 + 16 * (n >> 2) + 4 * q + (n & 3);
            const unsigned int ent2 = bb[(eloc < cnt) ? eloc : 0];
            r2 = (int)(ent2 >> 24);
            u2 = (eloc < cnt) ? u[ent2 & 0x1FFFFu] : 0.0f;
        }
        // ---- P gathers: row from 16KB window, col from L2-resident P2 ----
        short8 v1[2], v2[2];
        #pragma unroll
        for (int t = 0; t < 2; ++t) {
            v1[t] = *(const short8*)(P1b + (size_t)rl[t] * 32 + q * 8);
            v2[t] = *(const short8*)(P2 + (size_t)cI[t] * 32 + q * 8);
        }

        // ---- layers 2+3 (R4-proven core; cvt_pk repack) ----
        float tr[2][4];
        #pragma unroll
        for (int t = 0; t < 2; ++t) {
            union VU { short8 s; unsigned int w[4]; };
            VU x1, x2, ar;
            x1.s = v1[t]; x2.s = v2[t];
            #pragma unroll
            for (int i = 0; i < 4; ++i) {
                const unsigned int w1 = x1.w[i], w2 = x2.w[i];
                float lo = __uint_as_float(w1 << 16) + __uint_as_float(w2 << 16);
                float hi = __uint_as_float(w1 & 0xFFFF0000u)
                         + __uint_as_float(w2 & 0xFFFF0000u);
                lo = fmaxf(lo, 0.0f);
                hi = fmaxf(hi, 0.0f);
                ar.w[i] = pk_bf16x2_rn(lo, hi);
            }
            const short8 a = ar.s;
            floatx4 d0 = {b2n0, b2n0, b2n0, b2n0};
            floatx4 d1 = {b2n1, b2n1, b2n1, b2n1};
            d0 = __builtin_amdgcn_mfma_f32_16x16x32_bf16(a, bf0, d0, 0, 0, 0);
            d1 = __builtin_amdgcn_mfma_f32_16x16x32_bf16(a, bf1, d1, 0, 0, 0);
            #pragma unroll
            for (int r = 0; r < 4; ++r)
                tr[t][r] = fmaxf(d0[r], 0.0f) * w3n0 + fmaxf(d1[r], 0.0f) * w3n1;
        }

        // ---- 16-lane row reduce-to-all: 4x v_add_f32 + DPP row_ror ----
        #pragma unroll
        for (int t = 0; t < 2; ++t)
            #pragma unroll
            for (int r = 0; r < 4; ++r) {
                float v = tr[t][r];
                v += DPP_ROR_F32(v, 1);
                v += DPP_ROR_F32(v, 2);
                v += DPP_ROR_F32(v, 4);
                v += DPP_ROR_F32(v, 8);
                tr[t][r] = v;
            }

        if (n < 8) {
            const float va0 = (n & 4) ? tr[1][0] : tr[0][0];
            const float va1 = (n & 4) ? tr[1][1] : tr[0][1];
            const float va2 = (n & 4) ? tr[1][2] : tr[0][2];
            const float va3 = (n & 4) ? tr[1][3] : tr[0][3];
            const float vb0 = (n & 2) ? va2 : va0;
            const float vb1 = (n & 2) ? va3 : va1;
            const float v   = (n & 1) ? vb1 : vb0;
            atomicAdd(&accs[r2], (v + bias3) * u2);
        }
    }

    __syncthreads();

    if (tid < 256) {
        const int node = b * 256 + tid;
        if (node < N_NODES) atomicAdd(out + node, accs[tid]);
    }
}

extern "C" void kernel_launch(void* const* d_in, const int* in_sizes, int n_in,
                              void* d_out, int out_size, void* d_ws, size_t ws_size,
                              hipStream_t stream)
{
    const float* x    = (const float*)d_in[0];
    const int*   eidx = (const int*)  d_in[1];   // [2, E] int32
    const float* u    = (const float*)d_in[2];
    const float* W1   = (const float*)d_in[3];
    const float* b1   = (const float*)d_in[4];
    const float* W2   = (const float*)d_in[5];
    const float* b2   = (const float*)d_in[6];
    const float* W3   = (const float*)d_in[7];
    const float* b3   = (const float*)d_in[8];

    const int* row = eidx;
    const int* col = eidx + N_EDGES;

    // ws layout: P1 3.2MB | P2 3.2MB | buf 5.62MB | cursor 784B
    unsigned short* P1 = (unsigned short*)d_ws;
    unsigned short* P2 = (unsigned short*)((char*)d_ws + (size_t)N_NODES * 64);
    unsigned int*  buf = (unsigned int*)((char*)d_ws + (size_t)N_NODES * 128);
    int* cursor = (int*)((char*)d_ws + (size_t)N_NODES * 128
                         + (size_t)N_BUCKETS * BUCKET_CAP * 4);
    float* out = (float*)d_out;

    // zero bucket cursors (784 B, must precede the binning blocks of D1)
    hipMemsetAsync(cursor, 0, N_BUCKETS * sizeof(int), stream);

    // D1: precompute P1/P2 + zero out  ||  bin edge IDs (concurrent halves)
    fused_pre_bin<<<D1_BLOCKS, 256, 0, stream>>>(
        x, W1, b1, row, col, P1, P2, buf, cursor, out);

    // D2: per-bucket MLP + LDS reduce -> out (512-thread blocks)
    bucket_mlp<<<N_BUCKETS * KB_SPLIT, 512, 0, stream>>>(
        u, W2, b2, W3, b3, P1, P2, buf, cursor, out);
}